// Round 2
// 219.179 us; speedup vs baseline: 1.0221x; 1.0221x over previous
//
#include <hip/hip_runtime.h>
#include <cmath>

typedef __bf16 bf16x8 __attribute__((ext_vector_type(8)));
typedef float f32x4 __attribute__((ext_vector_type(4)));
typedef unsigned short u16;

#define MFMA_BF16 __builtin_amdgcn_mfma_f32_16x16x32_bf16

// round-to-nearest-even fp32 -> bf16 (bit pattern)
__device__ __forceinline__ u16 f2bf(float f) {
  unsigned int u = __float_as_uint(f);
  u = (u + 0x7fffu + ((u >> 16) & 1u)) >> 16;
  return (u16)u;
}

// fast round for P (half-up, tolerance-safe, 2 VALU)
__device__ __forceinline__ unsigned pbf(float f) {
  return (__float_as_uint(f) + 0x8000u) >> 16;
}

// async global->LDS, 16B per lane. LDS dest must be wave-uniform base + lane*16.
__device__ __forceinline__ void async16(const u16* g, u16* l) {
  __builtin_amdgcn_global_load_lds(
      (__attribute__((address_space(1))) void*)g,
      (__attribute__((address_space(3))) void*)l, 16, 0, 0);
}

// ---------------------------------------------------------------- converts
__global__ __launch_bounds__(256) void cvt_bf16(const float4* __restrict__ in,
                                                uint2* __restrict__ out, int n4) {
  int i = blockIdx.x * 256 + threadIdx.x;
  if (i >= n4) return;
  float4 f = in[i];
  uint2 o;
  o.x = (unsigned)f2bf(f.x) | ((unsigned)f2bf(f.y) << 16);
  o.y = (unsigned)f2bf(f.z) | ((unsigned)f2bf(f.w) << 16);
  out[i] = o;
}

// fused convert of q,k,v (1572864 float4 each) + 4 weights (147456 float4 each)
__global__ __launch_bounds__(256) void cvt_all(
    const float4* s0, const float4* s1, const float4* s2, const float4* s3,
    const float4* s4, const float4* s5, const float4* s6,
    uint2* d0, uint2* d1, uint2* d2, uint2* d3, uint2* d4, uint2* d5, uint2* d6) {
  int i = blockIdx.x * 256 + threadIdx.x;  // grid sized exactly: 5308416 / 256
  const float4* src;
  uint2* dst;
  int off;
  if (i < 1572864)      { src = s0; dst = d0; off = i; }
  else if (i < 3145728) { src = s1; dst = d1; off = i - 1572864; }
  else if (i < 4718592) { src = s2; dst = d2; off = i - 3145728; }
  else {
    int j = i - 4718592;
    int w = j / 147456;
    off = j - w * 147456;
    src = (w == 0) ? s3 : (w == 1) ? s4 : (w == 2) ? s5 : s6;
    dst = (w == 0) ? d3 : (w == 1) ? d4 : (w == 2) ? d5 : d6;
  }
  float4 f = src[off];
  uint2 o;
  o.x = (unsigned)f2bf(f.x) | ((unsigned)f2bf(f.y) << 16);
  o.y = (unsigned)f2bf(f.z) | ((unsigned)f2bf(f.w) << 16);
  dst[off] = o;
}

// ---------------------------------------------------------------- GEMM
// C[m, d] = sum_c A[m,c] * W[d,c].  Tile 128x64, BK=64, 4 waves of 32x64.
// 2-phase double-buffered: prefetch K-step t+1 (async16) BEFORE computing t,
// one barrier per K-step (T3-min). LDS 48 KB -> 3 blocks/CU.
// mode 0: q -> rope + *(0.125*log2e), layout [b][h][n][dh] (bf16)
// mode 1: k -> rope,                  layout [b][h][n][dh] (bf16)
// mode 2: v ->                        layout [b][h][dh][n] (bf16, transposed)
// mode 3: out = C + bias              layout [m][d]        (fp32)
__device__ __forceinline__ void gemm_body(const u16* __restrict__ Ag,
                                          const u16* __restrict__ Wg,
                                          void* __restrict__ OutP,
                                          const float* __restrict__ bias,
                                          int mode, int bx, int by) {
  __shared__ alignas(16) u16 As[2][128][64];  // 2 x 16 KB, xor-swizzled chunks
  __shared__ alignas(16) u16 Bs[2][64][64];   // 2 x  8 KB
  const int tid  = threadIdx.x;
  const int lane = tid & 63, wv = tid >> 6;
  const int l15  = lane & 15, quad = lane >> 4;
  const int row0 = bx * 128, col0 = by * 64;
  const int wm = wv * 32;
  const int swA = l15 & 7;  // read-side xor swizzle key (row&7 == l15&7 here)

  // hoisted staging offsets (A: 128 rows x 8 chunks; B: 64 rows x 8 chunks)
  size_t aSrc[4], bSrc[2];
  int aDst[4], bDst[2];
#pragma unroll
  for (int rr = 0; rr < 4; ++rr) {
    int c = rr * 256 + tid;
    int row = c >> 3, cp = c & 7;
    int gc = cp ^ (row & 7);
    aSrc[rr] = (size_t)(row0 + row) * 768 + gc * 8;
    aDst[rr] = c * 8;  // == row*64 + cp*8
  }
#pragma unroll
  for (int rr = 0; rr < 2; ++rr) {
    int c = rr * 256 + tid;
    int row = c >> 3, cp = c & 7;
    int gc = cp ^ (row & 7);
    bSrc[rr] = (size_t)(col0 + row) * 768 + gc * 8;
    bDst[rr] = c * 8;
  }

  auto stage = [&](int kb, int bf) {
#pragma unroll
    for (int rr = 0; rr < 4; ++rr) async16(&Ag[aSrc[rr] + kb], &((u16*)As[bf])[aDst[rr]]);
#pragma unroll
    for (int rr = 0; rr < 2; ++rr) async16(&Wg[bSrc[rr] + kb], &((u16*)Bs[bf])[bDst[rr]]);
  };

  f32x4 acc[2][4];
#pragma unroll
  for (int i = 0; i < 2; ++i)
#pragma unroll
    for (int j = 0; j < 4; ++j) acc[i][j] = (f32x4){0.f, 0.f, 0.f, 0.f};

  stage(0, 0);
  __syncthreads();

  auto step = [&](int kb, int rb) {
    if (kb < 704) stage(kb + 64, rb ^ 1);  // prefetch next K-step while computing
#pragma unroll
    for (int kd = 0; kd < 2; ++kd) {
      int cpk = (((kd * 4 + quad) ^ swA)) * 8;
      bf16x8 af[2], bfr[4];
      af[0] = *(const bf16x8*)&As[rb][wm + l15][cpk];
      af[1] = *(const bf16x8*)&As[rb][wm + 16 + l15][cpk];
#pragma unroll
      for (int nt = 0; nt < 4; ++nt) bfr[nt] = *(const bf16x8*)&Bs[rb][nt * 16 + l15][cpk];
#pragma unroll
      for (int mt = 0; mt < 2; ++mt)
#pragma unroll
        for (int nt = 0; nt < 4; ++nt)
          acc[mt][nt] = MFMA_BF16(af[mt], bfr[nt], acc[mt][nt], 0, 0, 0);
    }
    __syncthreads();  // drains vmcnt: prefetch landed; buffer swap safe
  };

  for (int kb = 0; kb < 768; kb += 128) {
    step(kb, 0);
    step(kb + 64, 1);
  }

  // C/D layout: col = l15, row = quad*4 + r
  if (mode == 3) {
    float* O = (float*)OutP;
#pragma unroll
    for (int mt = 0; mt < 2; ++mt)
#pragma unroll
      for (int r = 0; r < 4; ++r) {
        int m = row0 + wm + mt * 16 + quad * 4 + r;
#pragma unroll
        for (int nt = 0; nt < 4; ++nt) {
          int c = col0 + nt * 16 + l15;
          O[(size_t)m * 768 + c] = acc[mt][nt][r] + bias[c];
        }
      }
  } else if (mode == 2) {
    u16* O = (u16*)OutP;
#pragma unroll
    for (int mt = 0; mt < 2; ++mt)
#pragma unroll
      for (int r = 0; r < 4; ++r) {
        int m = row0 + wm + mt * 16 + quad * 4 + r;
        int b = m >> 10, n = m & 1023;
#pragma unroll
        for (int nt = 0; nt < 4; ++nt) {
          int c = col0 + nt * 16 + l15;  // h*64+dh
          O[(size_t)(b * 768 + c) * 1024 + n] = f2bf(acc[mt][nt][r]);
        }
      }
  } else {
    // q/k rope. col0 is head-aligned (64-col tile == one head): dh = nt*16+l15,
    // nt in {0,1} pairs with nt+2 (dh+32) on the SAME lane.
    u16* O = (u16*)OutP;
    // mode 0 also folds log2(e) so attention can use exp2 directly.
    const float scale = (mode == 0) ? 0.125f * 1.44269504088896f : 1.0f;
    const float invf0 = exp2f(-6.6438561897747395f * (float)l15 * (1.0f / 32.0f));
    const float invf1 = exp2f(-6.6438561897747395f * (float)(16 + l15) * (1.0f / 32.0f));
#pragma unroll
    for (int mt = 0; mt < 2; ++mt)
#pragma unroll
      for (int r = 0; r < 4; ++r) {
        int m = row0 + wm + mt * 16 + quad * 4 + r;
        int b = m >> 10, n = m & 1023;
        float fn = (float)n;
        size_t rowbase = (size_t)b * 786432 + (size_t)n * 64;
#pragma unroll
        for (int nt = 0; nt < 2; ++nt) {
          float sv, cv;
          __sincosf(fn * (nt ? invf1 : invf0), &sv, &cv);
          float x1 = acc[mt][nt][r], x2 = acc[mt][nt + 2][r];
          int c1 = col0 + nt * 16 + l15;
          int c2 = c1 + 32;
          O[rowbase + (size_t)(c1 >> 6) * 65536 + (c1 & 63)] = f2bf((x1 * cv - x2 * sv) * scale);
          O[rowbase + (size_t)(c2 >> 6) * 65536 + (c2 & 63)] = f2bf((x2 * cv + x1 * sv) * scale);
        }
      }
  }
}

__global__ __launch_bounds__(256, 3) void gemm768(const u16* __restrict__ A,
                                                  const u16* __restrict__ W,
                                                  void* __restrict__ OutP,
                                                  const float* __restrict__ bias,
                                                  int mode) {
  gemm_body(A, W, OutP, bias, mode, blockIdx.x, blockIdx.y);
}

__global__ __launch_bounds__(256, 3) void gemm_qkv(
    const u16* __restrict__ xq, const u16* __restrict__ xk, const u16* __restrict__ xv,
    const u16* __restrict__ wq, const u16* __restrict__ wk, const u16* __restrict__ wv,
    u16* __restrict__ qb, u16* __restrict__ kb, u16* __restrict__ vtb) {
  int z = blockIdx.z;
  const u16* A = (z == 0) ? xq : (z == 1) ? xk : xv;
  const u16* W = (z == 0) ? wq : (z == 1) ? wk : wv;
  void* O      = (z == 0) ? (void*)qb : (z == 1) ? (void*)kb : (void*)vtb;
  gemm_body(A, W, O, nullptr, z, blockIdx.x, blockIdx.y);
}

// ---------------------------------------------------------------- attention
// Per block: 128 Q rows of one (b,h); 4 waves x 32 rows. q pre-scaled by
// 0.125*log2e so P = exp2(S) == softmax numerator exactly.
//
// SWAPPED-OPERAND structure: S^T = mfma(K, Q) -> lane holds, per query col
// l15, keys ct*16+quad*4+r (4 CONSECUTIVE key positions per ct). P therefore
// packs to b64 LDS writes in a [query][key] per-wave tile (stride 72,
// 16B-aligned rows), and PV's B-frag (P^T rows ks*32+quad*8+j, col l15) reads
// back as one b128. PV: O^T = mfma(V^T, P^T); the V^T A-frag is the exact
// swizzled VsF read pattern. Output lands d-contiguous (4/lane) -> 8B stores;
// row-sum reduces with 2 shuffles (xor 16/32).
//
// K/V double-buffered; tile t+1 prefetched (async16) BEFORE computing tile t;
// one barrier per tile (T3-min). LDS 50 KB -> 3 blocks/CU (grid-limited).
// grid (96, 8): bh = blockIdx.x so a head's 8 q-tiles land on ONE XCD.
__global__ __launch_bounds__(256, 3) void attn_fused(const u16* __restrict__ Q,
                                                     const u16* __restrict__ K,
                                                     const u16* __restrict__ Vt,
                                                     u16* __restrict__ X) {
  __shared__ alignas(16) u16 KsF[2][4096];  // [buf][kd*2048 + key*32 + chunk], xor-swizzled
  __shared__ alignas(16) u16 VsF[2][4096];  // [buf][ks*2048 + dh*32 + chunk], xor-swizzled
  __shared__ alignas(16) u16 Ps[4][2304];   // per-wave P [32 query][72]; also Q staging

  const int tid  = threadIdx.x;
  const int lane = tid & 63, wv = tid >> 6;
  const int l15  = lane & 15, quad = lane >> 4;
  const int bh = blockIdx.x, qt = blockIdx.y;
  const size_t base = (size_t)bh * 65536;
  const int sw8 = (quad ^ ((l15 >> 1) & 3)) * 8;  // frag-read swizzle offset (elems)

  const u16* Qg = Q + base + (size_t)qt * 8192;
  const u16* Kb = K + base;
  const u16* Vb = Vt + base;

  // hoisted staging offsets (K: 2 chunks/thread, V: 2 chunks/thread)
  int kOff[2], vOff[2], dOff[2];
#pragma unroll
  for (int rr = 0; rr < 2; ++rr) {
    int c = rr * 256 + tid;
    int sub = c >> 8, rowi = (c >> 2) & 63, colc = c & 3;
    int cs = (colc ^ ((rowi >> 1) & 3)) * 8;  // fetch the chunk this slot holds
    kOff[rr] = rowi * 64 + sub * 32 + cs;
    vOff[rr] = rowi * 1024 + sub * 32 + cs;
    dOff[rr] = c * 8;
  }

  auto stageKV = [&](int kt, int bf) {
#pragma unroll
    for (int rr = 0; rr < 2; ++rr) {
      async16(&Kb[(size_t)kt * 64 + kOff[rr]], &KsF[bf][dOff[rr]]);
      async16(&Vb[(size_t)kt + vOff[rr]], &VsF[bf][dOff[rr]]);
    }
  };

  // stage Q (borrows Ps storage: 16 KB needed, 18 KB available) + tile 0
  u16* Pflat = &Ps[0][0];
#pragma unroll
  for (int rr = 0; rr < 4; ++rr) {
    int c = rr * 256 + tid;
    async16(&Qg[c * 8], &Pflat[c * 8]);
  }
  stageKV(0, 0);
  __syncthreads();

  bf16x8 qf[2][2];
#pragma unroll
  for (int mt = 0; mt < 2; ++mt)
#pragma unroll
    for (int kd = 0; kd < 2; ++kd)
      qf[mt][kd] = *(const bf16x8*)&Pflat[(wv * 32 + mt * 16 + l15) * 64 + kd * 32 + quad * 8];
  __syncthreads();  // all waves done with Q staging before Ps reused for P

  f32x4 o[2][4];
  float lsum[2] = {0.f, 0.f};
#pragma unroll
  for (int mt = 0; mt < 2; ++mt)
#pragma unroll
    for (int nt = 0; nt < 4; ++nt) o[mt][nt] = (f32x4){0.f, 0.f, 0.f, 0.f};

  u16* Pw = &Ps[wv][0];
  const int prow0 = l15 * 72, prow1 = (16 + l15) * 72;

  auto tile = [&](int t, int rb) {
    if (t < 15) stageKV((t + 1) * 64, rb ^ 1);  // prefetch next K/V tile

    // S^T = K Q^T: lane holds key = ct*16+quad*4+r, query = mt*16+l15
    f32x4 s[2][4];
#pragma unroll
    for (int ct = 0; ct < 4; ++ct) {
      bf16x8 kf0 = *(const bf16x8*)&KsF[rb][(ct * 16 + l15) * 32 + sw8];
      bf16x8 kf1 = *(const bf16x8*)&KsF[rb][2048 + (ct * 16 + l15) * 32 + sw8];
#pragma unroll
      for (int mt = 0; mt < 2; ++mt) {
        f32x4 tacc = (f32x4){0.f, 0.f, 0.f, 0.f};
        tacc = MFMA_BF16(kf0, qf[mt][0], tacc, 0, 0, 0);
        tacc = MFMA_BF16(kf1, qf[mt][1], tacc, 0, 0, 0);
        s[mt][ct] = tacc;
      }
    }

    // P = exp2(S); 4 consecutive keys/lane -> one b64 write per (mt,ct)
#pragma unroll
    for (int mt = 0; mt < 2; ++mt) {
#pragma unroll
      for (int ct = 0; ct < 4; ++ct) {
        float p0 = __builtin_amdgcn_exp2f(s[mt][ct][0]);
        float p1 = __builtin_amdgcn_exp2f(s[mt][ct][1]);
        float p2 = __builtin_amdgcn_exp2f(s[mt][ct][2]);
        float p3 = __builtin_amdgcn_exp2f(s[mt][ct][3]);
        lsum[mt] += (p0 + p1) + (p2 + p3);
        uint2 w;
        w.x = pbf(p0) | (pbf(p1) << 16);
        w.y = pbf(p2) | (pbf(p3) << 16);
        *(uint2*)&Pw[(mt ? prow1 : prow0) + ct * 16 + quad * 4] = w;
      }
    }

    // O^T += V^T P^T (wave-local LDS round-trip; compiler orders via lgkmcnt)
#pragma unroll
    for (int ks = 0; ks < 2; ++ks) {
      bf16x8 pf0 = *(const bf16x8*)&Pw[prow0 + ks * 32 + quad * 8];
      bf16x8 pf1 = *(const bf16x8*)&Pw[prow1 + ks * 32 + quad * 8];
#pragma unroll
      for (int nt = 0; nt < 4; ++nt) {
        bf16x8 vf = *(const bf16x8*)&VsF[rb][ks * 2048 + (nt * 16 + l15) * 32 + sw8];
        o[0][nt] = MFMA_BF16(vf, pf0, o[0][nt], 0, 0, 0);
        o[1][nt] = MFMA_BF16(vf, pf1, o[1][nt], 0, 0, 0);
      }
    }
    __syncthreads();  // drains vmcnt: prefetch landed; buffer swap safe
  };

  for (int t = 0; t < 16; t += 2) {
    tile(t, 0);
    tile(t + 1, 1);
  }

  // epilogue: lane holds O[query = mt*16+l15][d = nt*16 + quad*4 + r]
  const int b = bh / 12, h = bh % 12;
#pragma unroll
  for (int mt = 0; mt < 2; ++mt) {
    float l = lsum[mt];
    l += __shfl_xor(l, 16);
    l += __shfl_xor(l, 32);
    float inv = __builtin_amdgcn_rcpf(l);
    int n = qt * 128 + wv * 32 + mt * 16 + l15;
    size_t rowoff = ((size_t)(b * 1024 + n)) * 768 + h * 64 + quad * 4;
#pragma unroll
    for (int nt = 0; nt < 4; ++nt) {
      uint2 w;
      w.x = (unsigned)f2bf(o[mt][nt][0] * inv) | ((unsigned)f2bf(o[mt][nt][1] * inv) << 16);
      w.y = (unsigned)f2bf(o[mt][nt][2] * inv) | ((unsigned)f2bf(o[mt][nt][3] * inv) << 16);
      *(uint2*)&X[rowoff + nt * 16] = w;
    }
  }
}

// ---------------------------------------------------------------- launch
extern "C" void kernel_launch(void* const* d_in, const int* in_sizes, int n_in,
                              void* d_out, int out_size, void* d_ws, size_t ws_size,
                              hipStream_t stream) {
  const float* qin = (const float*)d_in[0];
  const float* kin = (const float*)d_in[1];
  const float* vin = (const float*)d_in[2];
  const float* Wq  = (const float*)d_in[3];
  const float* Wk  = (const float*)d_in[4];
  const float* Wv  = (const float*)d_in[5];
  const float* Wo  = (const float*)d_in[6];
  const float* bo  = (const float*)d_in[7];
  char* ws = (char*)d_ws;

  if (ws_size >= 80216064) {
    // big-ws path: per-input bf16 buffers -> one fused convert + one fused QKV GEMM
    u16* xq16 = (u16*)(ws + 0);
    u16* xk16 = (u16*)(ws + 12582912);
    u16* xv16 = (u16*)(ws + 25165824);
    u16* qb   = (u16*)(ws + 37748736);
    u16* kb   = (u16*)(ws + 50331648);
    u16* vtb  = (u16*)(ws + 62914560);
    u16* wq16 = (u16*)(ws + 75497472);
    u16* wk16 = wq16 + 589824;
    u16* wv16 = wk16 + 589824;
    u16* wo16 = wv16 + 589824;
    u16* X    = xq16;  // reuse after QKV GEMMs consume xq16

    cvt_all<<<20736, 256, 0, stream>>>(
        (const float4*)qin, (const float4*)kin, (const float4*)vin,
        (const float4*)Wq, (const float4*)Wk, (const float4*)Wv, (const float4*)Wo,
        (uint2*)xq16, (uint2*)xk16, (uint2*)xv16,
        (uint2*)wq16, (uint2*)wk16, (uint2*)wv16, (uint2*)wo16);
    gemm_qkv<<<dim3(64, 12, 3), 256, 0, stream>>>(xq16, xk16, xv16, wq16, wk16, wv16,
                                                  qb, kb, vtb);
    attn_fused<<<dim3(96, 8), 256, 0, stream>>>(qb, kb, vtb, X);
    gemm768<<<dim3(64, 12), 256, 0, stream>>>(X, wo16, d_out, bo, 3);
  } else {
    // fallback: round-1 55 MB layout, sequential converts sharing one buffer
    u16* xbuf = (u16*)(ws + 0);
    u16* qb   = (u16*)(ws + 12582912);
    u16* kb   = (u16*)(ws + 25165824);
    u16* vtb  = (u16*)(ws + 37748736);
    u16* wq16 = (u16*)(ws + 50331648);
    u16* wk16 = wq16 + 589824;
    u16* wv16 = wk16 + 589824;
    u16* wo16 = wv16 + 589824;

    cvt_bf16<<<576, 256, 0, stream>>>((const float4*)Wq, (uint2*)wq16, 147456);
    cvt_bf16<<<576, 256, 0, stream>>>((const float4*)Wk, (uint2*)wk16, 147456);
    cvt_bf16<<<576, 256, 0, stream>>>((const float4*)Wv, (uint2*)wv16, 147456);
    cvt_bf16<<<576, 256, 0, stream>>>((const float4*)Wo, (uint2*)wo16, 147456);

    dim3 ggrid(64, 12);
    cvt_bf16<<<6144, 256, 0, stream>>>((const float4*)qin, (uint2*)xbuf, 1572864);
    gemm768<<<ggrid, 256, 0, stream>>>(xbuf, wq16, (void*)qb, nullptr, 0);
    cvt_bf16<<<6144, 256, 0, stream>>>((const float4*)kin, (uint2*)xbuf, 1572864);
    gemm768<<<ggrid, 256, 0, stream>>>(xbuf, wk16, (void*)kb, nullptr, 1);
    cvt_bf16<<<6144, 256, 0, stream>>>((const float4*)vin, (uint2*)xbuf, 1572864);
    gemm768<<<ggrid, 256, 0, stream>>>(xbuf, wv16, (void*)vtb, nullptr, 2);

    attn_fused<<<dim3(96, 8), 256, 0, stream>>>(qb, kb, vtb, xbuf);

    gemm768<<<ggrid, 256, 0, stream>>>(xbuf, wo16, d_out, bo, 3);
  }
}